// Round 5
// baseline (1384.531 us; speedup 1.0000x reference)
//
#include <hip/hip_runtime.h>

// ---- transpose: x (B=64,I=8,C=2048) -> xt[c][i][b]  (i*64+b inner) ----
__global__ __launch_bounds__(256) void transpose_kernel(const float* __restrict__ x,
                                                        float* __restrict__ xt) {
    __shared__ float tile[64][65];
    const int bi0 = (blockIdx.x >> 5) << 6;    // 8 bi-tiles (bi = b*8+i)
    const int c0  = (blockIdx.x & 31) << 6;    // 32 c-tiles
    const int tx = threadIdx.x & 63, ty = threadIdx.x >> 6;
#pragma unroll
    for (int p = 0; p < 16; ++p)
        tile[ty + p * 4][tx] = x[(size_t)(bi0 + ty + p * 4) * 2048 + c0 + tx];
    __syncthreads();
#pragma unroll
    for (int p = 0; p < 16; ++p) {
        int bi = bi0 + tx;
        xt[(size_t)(c0 + ty + p * 4) * 512 + (bi & 7) * 64 + (bi >> 3)] = tile[tx][ty + p * 4];
    }
}

// ---- s-pass: part[chunk][u][d][b] = sum_{c in chunk} sum_i W[c,u,d,i]*(cij[c,u]*x[b,i,c])
// grid = 32 chunks(64c) x 32 u = 1024 blocks; block 256 = 4 waves.
// x slabs (8c = 16KB) double-buffered in LDS, cij premultiplied at staging.
// lane: dg = l>>4 (d-group), bq = l&15 (b-quad) -> 16 acc.
template <int UNIFORM>
__global__ __launch_bounds__(256, 4) void s_kernel5(const float* __restrict__ xt,
                                                    const float* __restrict__ W,
                                                    const float* __restrict__ cij,
                                                    float* __restrict__ part) {
    const int chunk = blockIdx.x >> 5;
    const int u     = blockIdx.x & 31;
    const int t = threadIdx.x, w = t >> 6, l = t & 63;
    const int dg = l >> 4, bq = l & 15;

    __shared__ float lds[8192];          // 2 x 4096 dbuf slabs; reused as red at end

    const int cbase = chunk * 64;

    float acc[16];
#pragma unroll
    for (int j = 0; j < 16; ++j) acc[j] = 0.f;

    // prologue: stage slab 0
    float4 st[4]; float cwst[4];
    {
        const float4* src = reinterpret_cast<const float4*>(xt + (size_t)cbase * 512);
#pragma unroll
        for (int k = 0; k < 4; ++k) st[k] = src[t + k * 256];
#pragma unroll
        for (int k = 0; k < 4; ++k)
            cwst[k] = UNIFORM ? 0.03125f : cij[(cbase + k * 2 + (t >> 7)) * 32 + u];
#pragma unroll
        for (int k = 0; k < 4; ++k) {
            float4 vq = st[k]; const float cw = cwst[k];
            vq.x *= cw; vq.y *= cw; vq.z *= cw; vq.w *= cw;
            *reinterpret_cast<float4*>(lds + t * 4 + k * 1024) = vq;
        }
    }
    __syncthreads();

#pragma unroll 2
    for (int sl = 0; sl < 8; ++sl) {
        const int pb = (sl & 1) * 4096;
        // T14: issue next-slab global loads before compute
        if (sl < 7) {
            const float4* src = reinterpret_cast<const float4*>(xt + (size_t)(cbase + (sl + 1) * 8) * 512);
#pragma unroll
            for (int k = 0; k < 4; ++k) st[k] = src[t + k * 256];
#pragma unroll
            for (int k = 0; k < 4; ++k)
                cwst[k] = UNIFORM ? 0.03125f : cij[(cbase + (sl + 1) * 8 + k * 2 + (t >> 7)) * 32 + u];
        }
        // compute this slab: wave w owns c-locals w*2, w*2+1
#pragma unroll
        for (int j = 0; j < 2; ++j) {
            const int cl = w * 2 + j;
            const int c  = cbase + sl * 8 + cl;
            const float4* Wp = reinterpret_cast<const float4*>(W + ((size_t)c * 32 + u) * 128 + dg * 32);
            float4 wv[8];
#pragma unroll
            for (int q = 0; q < 8; ++q) wv[q] = Wp[q];
            float4 xv[8];
#pragma unroll
            for (int q = 0; q < 8; ++q)
                xv[q] = *reinterpret_cast<const float4*>(lds + pb + cl * 512 + q * 64 + bq * 4);
#pragma unroll
            for (int dd = 0; dd < 4; ++dd) {
                const float4 wa = wv[dd * 2], wb = wv[dd * 2 + 1];
                acc[dd * 4 + 0] += wa.x * xv[0].x + wa.y * xv[1].x + wa.z * xv[2].x + wa.w * xv[3].x
                                 + wb.x * xv[4].x + wb.y * xv[5].x + wb.z * xv[6].x + wb.w * xv[7].x;
                acc[dd * 4 + 1] += wa.x * xv[0].y + wa.y * xv[1].y + wa.z * xv[2].y + wa.w * xv[3].y
                                 + wb.x * xv[4].y + wb.y * xv[5].y + wb.z * xv[6].y + wb.w * xv[7].y;
                acc[dd * 4 + 2] += wa.x * xv[0].z + wa.y * xv[1].z + wa.z * xv[2].z + wa.w * xv[3].z
                                 + wb.x * xv[4].z + wb.y * xv[5].z + wb.z * xv[6].z + wb.w * xv[7].z;
                acc[dd * 4 + 3] += wa.x * xv[0].w + wa.y * xv[1].w + wa.z * xv[2].w + wa.w * xv[3].w
                                 + wb.x * xv[4].w + wb.y * xv[5].w + wb.z * xv[6].w + wb.w * xv[7].w;
            }
        }
        // write staged next slab, then barrier
        if (sl < 7) {
            const int pn = ((sl + 1) & 1) * 4096;
#pragma unroll
            for (int k = 0; k < 4; ++k) {
                float4 vq = st[k]; const float cw = cwst[k];
                vq.x *= cw; vq.y *= cw; vq.z *= cw; vq.w *= cw;
                *reinterpret_cast<float4*>(lds + pn + t * 4 + k * 1024) = vq;
            }
        }
        __syncthreads();
    }

    // cross-wave reduce: reuse lds as red[(w*64+l)*17 + j]
#pragma unroll
    for (int j = 0; j < 16; ++j) lds[(w * 64 + l) * 17 + j] = acc[j];
    __syncthreads();
    const int l2 = t & 63, k = t >> 6;
    const int dg2 = l2 >> 4, bq2 = l2 & 15;
    float4 o;
    float* op = &o.x;
#pragma unroll
    for (int bb = 0; bb < 4; ++bb)
        op[bb] = lds[(0 * 64 + l2) * 17 + k * 4 + bb] + lds[(1 * 64 + l2) * 17 + k * 4 + bb]
               + lds[(2 * 64 + l2) * 17 + k * 4 + bb] + lds[(3 * 64 + l2) * 17 + k * 4 + bb];
    *reinterpret_cast<float4*>(part + (((size_t)chunk * 32 + u) * 16 + dg2 * 4 + k) * 64 + bq2 * 4) = o;
}

// ---- s[u][d][b] = sum over 32 chunks, float4-vectorized ----
__global__ __launch_bounds__(256) void reduce_kernel(const float4* __restrict__ part4,
                                                     float4* __restrict__ s4) {
    int n = blockIdx.x * 256 + threadIdx.x;     // grid = 32 -> 8192 float4
    float4 a = part4[n];
#pragma unroll
    for (int k = 1; k < 32; ++k) {
        float4 b = part4[(size_t)k * 8192 + n];
        a.x += b.x; a.y += b.y; a.z += b.z; a.w += b.w;
    }
    s4[n] = a;
}

// ---- squash (reference quirk: mag over U per (b,d)); s layout [u][d][b] ----
__global__ __launch_bounds__(256) void v_kernel2(const float* __restrict__ s,
                                                 float* __restrict__ v,
                                                 float* __restrict__ out) {
    int n = blockIdx.x * 256 + threadIdx.x;     // grid = 4 -> 1024 = B*D
    int b = n >> 4, d = n & 15;
    float sv[32];
    float msq = 0.f;
#pragma unroll
    for (int u = 0; u < 32; ++u) {
        sv[u] = s[(u * 16 + d) * 64 + b];
        msq += sv[u] * sv[u];
    }
    float scale = msq / ((1.f + msq) * sqrtf(msq));
#pragma unroll
    for (int u = 0; u < 32; ++u) {
        float val = sv[u] * scale;
        v[(b * 32 + u) * 16 + d] = val;
        out[(b * 32 + u) * 16 + d] = val;
    }
}

// ---- delta + fused softmax: bij[c,u] (=|+=) (1/B) sum uh*v ; cij = softmax_u(bij)
// grid = 1024 (2 c per block); block 256; lane: u = t>>3, d-pair = (t&7)*2
template <int FIRST>
__global__ __launch_bounds__(256) void delta_kernel6(const float* __restrict__ xt,
                                                     const float* __restrict__ W,
                                                     const float* __restrict__ v,
                                                     float* __restrict__ bij,
                                                     float* __restrict__ cij) {
    const int c0 = blockIdx.x * 2;
    const int t = threadIdx.x;
    __shared__ float xs[1024];                  // [cc][b][i]
    __shared__ float sm[64];
    {
        const float4 vq = reinterpret_cast<const float4*>(xt + (size_t)c0 * 512)[t];
        const float* pf = &vq.x;
        const int k = t * 4;
#pragma unroll
        for (int j2 = 0; j2 < 4; ++j2) {
            int e = k + j2, cl = e >> 9, rem = e & 511, i = rem >> 6, b = rem & 63;
            xs[cl * 512 + b * 8 + i] = pf[j2];
        }
    }
    __syncthreads();
    const int u = t >> 3, d0 = (t & 7) * 2;
    const float4* W0 = reinterpret_cast<const float4*>(W + ((size_t)c0 * 32 + u) * 128 + d0 * 8);
    const float4* W1 = reinterpret_cast<const float4*>(W + ((size_t)(c0 + 1) * 32 + u) * 128 + d0 * 8);
    const float4 a00 = W0[0], a01 = W0[1], a10 = W0[2], a11 = W0[3];
    const float4 b00 = W1[0], b01 = W1[1], b10 = W1[2], b11 = W1[3];
    float p0 = 0.f, p1 = 0.f;
#pragma unroll 4
    for (int b = 0; b < 64; ++b) {
        const float2 vv = *reinterpret_cast<const float2*>(v + (b * 32 + u) * 16 + d0);
        {
            const float4 xa = *reinterpret_cast<const float4*>(xs + b * 8);
            const float4 xb = *reinterpret_cast<const float4*>(xs + b * 8 + 4);
            float uh0 = a00.x * xa.x + a00.y * xa.y + a00.z * xa.z + a00.w * xa.w
                      + a01.x * xb.x + a01.y * xb.y + a01.z * xb.z + a01.w * xb.w;
            float uh1 = a10.x * xa.x + a10.y * xa.y + a10.z * xa.z + a10.w * xa.w
                      + a11.x * xb.x + a11.y * xb.y + a11.z * xb.z + a11.w * xb.w;
            p0 += uh0 * vv.x + uh1 * vv.y;
        }
        {
            const float4 xa = *reinterpret_cast<const float4*>(xs + 512 + b * 8);
            const float4 xb = *reinterpret_cast<const float4*>(xs + 512 + b * 8 + 4);
            float uh0 = b00.x * xa.x + b00.y * xa.y + b00.z * xa.z + b00.w * xa.w
                      + b01.x * xb.x + b01.y * xb.y + b01.z * xb.z + b01.w * xb.w;
            float uh1 = b10.x * xa.x + b10.y * xa.y + b10.z * xa.z + b10.w * xa.w
                      + b11.x * xb.x + b11.y * xb.y + b11.z * xb.z + b11.w * xb.w;
            p1 += uh0 * vv.x + uh1 * vv.y;
        }
    }
    p0 += __shfl_xor(p0, 1); p0 += __shfl_xor(p0, 2); p0 += __shfl_xor(p0, 4);
    p1 += __shfl_xor(p1, 1); p1 += __shfl_xor(p1, 2); p1 += __shfl_xor(p1, 4);
    if ((t & 7) == 0) {
        float r0 = p0 * (1.0f / 64.0f), r1 = p1 * (1.0f / 64.0f);
        if (!FIRST) { r0 += bij[c0 * 32 + u]; r1 += bij[(c0 + 1) * 32 + u]; }
        bij[c0 * 32 + u] = r0; bij[(c0 + 1) * 32 + u] = r1;
        sm[u] = r0; sm[32 + u] = r1;
    }
    __syncthreads();
    if (t < 64) {                                // wave 0: softmax per 32-lane half
        float val = sm[t];
        float m = val;
#pragma unroll
        for (int mask = 16; mask >= 1; mask >>= 1) m = fmaxf(m, __shfl_xor(m, mask));
        float e = expf(val - m);
        float ssum = e;
#pragma unroll
        for (int mask = 16; mask >= 1; mask >>= 1) ssum += __shfl_xor(ssum, mask);
        cij[(c0 + (t >> 5)) * 32 + (t & 31)] = e / ssum;
    }
}

extern "C" void kernel_launch(void* const* d_in, const int* in_sizes, int n_in,
                              void* d_out, int out_size, void* d_ws, size_t ws_size,
                              hipStream_t stream) {
    const float* x = (const float*)d_in[0];   // (B, I, C) = (64, 8, 2048)
    const float* W = (const float*)d_in[1];   // (C, U, D, I) = (2048, 32, 16, 8)
    float* out = (float*)d_out;               // (B, U, D, 1) flat = 32768 fp32

    float* ws   = (float*)d_ws;
    float* xt   = ws;                   // C*I*B    = 1,048,576 floats  [c][i][b]
    float* bij  = xt + 1048576;         // C*U      = 65,536
    float* cij  = bij + 65536;          // C*U      = 65,536
    float* s    = cij + 65536;          // U*D*B    = 32,768
    float* v    = s + 32768;            // B*U*D    = 32,768
    float* part = v + 32768;            // 32*U*D*B = 1,048,576

    transpose_kernel<<<256, 256, 0, stream>>>(x, xt);

    // it 0: cij uniform 1/32 (bij=0); delta writes bij and produces cij
    s_kernel5<1><<<1024, 256, 0, stream>>>(xt, W, cij, part);
    reduce_kernel<<<32, 256, 0, stream>>>((const float4*)part, (float4*)s);
    v_kernel2<<<4, 256, 0, stream>>>(s, v, out);
    delta_kernel6<1><<<1024, 256, 0, stream>>>(xt, W, v, bij, cij);

    // it 1
    s_kernel5<0><<<1024, 256, 0, stream>>>(xt, W, cij, part);
    reduce_kernel<<<32, 256, 0, stream>>>((const float4*)part, (float4*)s);
    v_kernel2<<<4, 256, 0, stream>>>(s, v, out);
    delta_kernel6<0><<<1024, 256, 0, stream>>>(xt, W, v, bij, cij);

    // it 2
    s_kernel5<0><<<1024, 256, 0, stream>>>(xt, W, cij, part);
    reduce_kernel<<<32, 256, 0, stream>>>((const float4*)part, (float4*)s);
    v_kernel2<<<4, 256, 0, stream>>>(s, v, out);
}

// Round 6
// 220.775 us; speedup vs baseline: 6.2712x; 6.2712x over previous
//
#include <hip/hip_runtime.h>

__device__ __forceinline__ void gload_lds16(const float* g, float* l) {
    __builtin_amdgcn_global_load_lds((const __attribute__((address_space(1))) void*)g,
                                     (__attribute__((address_space(3))) void*)l, 16, 0, 0);
}

// ---- transpose: x (B=64,I=8,C=2048) -> xt[c][i][b] ----
__global__ __launch_bounds__(256) void transpose_kernel(const float* __restrict__ x,
                                                        float* __restrict__ xt) {
    __shared__ float tile[64][65];
    const int bi0 = (blockIdx.x >> 5) << 6;    // bi = b*8+i
    const int c0  = (blockIdx.x & 31) << 6;
    const int tx = threadIdx.x & 63, ty = threadIdx.x >> 6;
#pragma unroll
    for (int p = 0; p < 16; ++p)
        tile[ty + p * 4][tx] = x[(size_t)(bi0 + ty + p * 4) * 2048 + c0 + tx];
    __syncthreads();
#pragma unroll
    for (int p = 0; p < 16; ++p) {
        int bi = bi0 + tx;
        xt[(size_t)(c0 + ty + p * 4) * 512 + (bi & 7) * 64 + (bi >> 3)] = tile[tx][ty + p * 4];
    }
}

// ---- s-pass: part[chunk][u][d][b] = sum_{c in chunk} cij[c,u]*sum_i W[c,u,d,i]*x[b,i,c]
// grid = 32 chunks(64c) x 32 u (u fast); block 256 = 4 waves.
// x slabs (8 c = 16KB) double-buffered via global_load_lds (no staging registers).
// Wave w stages floats [w*1024, w*1024+1024) of the slab = c-locals {2w, 2w+1},
// which are exactly the c's it computes -> LDS reads stay wave-local.
// lane: dg = l>>4 (d-group), bq = l&15 (b-quad) -> acc[16].
template <int UNIFORM>
__global__ __launch_bounds__(256) void s_kernel7(const float* __restrict__ xt,
                                                 const float* __restrict__ W,
                                                 const float* __restrict__ cij,
                                                 float* __restrict__ part) {
    const int chunk = blockIdx.x >> 5;
    const int u     = blockIdx.x & 31;
    const int t = threadIdx.x, w = t >> 6, l = t & 63;
    const int dg = l >> 4, bq = l & 15;

    __shared__ float xbuf[8192];          // 2 x 16KB slabs; reused as red at end

    const int cbase = chunk * 64;
    float acc[16];
#pragma unroll
    for (int j = 0; j < 16; ++j) acc[j] = 0.f;

    // prologue: stage slab 0 into buf 0
    {
        const float* g = xt + (size_t)cbase * 512 + w * 1024 + l * 4;
#pragma unroll
        for (int k = 0; k < 4; ++k)
            gload_lds16(g + k * 256, xbuf + w * 1024 + k * 256);
    }
    __syncthreads();

#pragma unroll 1
    for (int sl = 0; sl < 8; ++sl) {
        const int cur = (sl & 1) * 4096;
        if (sl < 7) {
            const int nxt = ((sl + 1) & 1) * 4096;
            const float* g = xt + (size_t)(cbase + (sl + 1) * 8) * 512 + w * 1024 + l * 4;
#pragma unroll
            for (int k = 0; k < 4; ++k)
                gload_lds16(g + k * 256, xbuf + nxt + w * 1024 + k * 256);
        }
        // compute: wave w owns c-locals 2w, 2w+1 of this slab
#pragma unroll 1
        for (int j = 0; j < 2; ++j) {
            const int cl = w * 2 + j;
            const int c  = cbase + sl * 8 + cl;
            const float cw = UNIFORM ? 0.03125f : cij[c * 32 + u];
            const float4* Wp = reinterpret_cast<const float4*>(W + ((size_t)c * 32 + u) * 128 + dg * 32);
            float4 wv[8];
#pragma unroll
            for (int q = 0; q < 8; ++q) wv[q] = Wp[q];
            float4 xv[8];
#pragma unroll
            for (int q = 0; q < 8; ++q)
                xv[q] = *reinterpret_cast<const float4*>(xbuf + cur + cl * 512 + q * 64 + bq * 4);
#pragma unroll
            for (int dd = 0; dd < 4; ++dd) {
                const float4 wa = wv[dd * 2], wb = wv[dd * 2 + 1];
                float uh0 = wa.x * xv[0].x + wa.y * xv[1].x + wa.z * xv[2].x + wa.w * xv[3].x
                          + wb.x * xv[4].x + wb.y * xv[5].x + wb.z * xv[6].x + wb.w * xv[7].x;
                float uh1 = wa.x * xv[0].y + wa.y * xv[1].y + wa.z * xv[2].y + wa.w * xv[3].y
                          + wb.x * xv[4].y + wb.y * xv[5].y + wb.z * xv[6].y + wb.w * xv[7].y;
                float uh2 = wa.x * xv[0].z + wa.y * xv[1].z + wa.z * xv[2].z + wa.w * xv[3].z
                          + wb.x * xv[4].z + wb.y * xv[5].z + wb.z * xv[6].z + wb.w * xv[7].z;
                float uh3 = wa.x * xv[0].w + wa.y * xv[1].w + wa.z * xv[2].w + wa.w * xv[3].w
                          + wb.x * xv[4].w + wb.y * xv[5].w + wb.z * xv[6].w + wb.w * xv[7].w;
                acc[dd * 4 + 0] += cw * uh0;
                acc[dd * 4 + 1] += cw * uh1;
                acc[dd * 4 + 2] += cw * uh2;
                acc[dd * 4 + 3] += cw * uh3;
            }
        }
        __syncthreads();
    }

    // cross-wave reduce: reuse xbuf (stride 17, conflict-free)
#pragma unroll
    for (int j = 0; j < 16; ++j) xbuf[(w * 64 + l) * 17 + j] = acc[j];
    __syncthreads();
    const int l2 = t & 63, k = t >> 6;
    const int dg2 = l2 >> 4, bq2 = l2 & 15;
    float4 o;
    float* op = &o.x;
#pragma unroll
    for (int bb = 0; bb < 4; ++bb)
        op[bb] = xbuf[(0 * 64 + l2) * 17 + k * 4 + bb] + xbuf[(1 * 64 + l2) * 17 + k * 4 + bb]
               + xbuf[(2 * 64 + l2) * 17 + k * 4 + bb] + xbuf[(3 * 64 + l2) * 17 + k * 4 + bb];
    *reinterpret_cast<float4*>(part + (((size_t)chunk * 32 + u) * 16 + dg2 * 4 + k) * 64 + bq2 * 4) = o;
}

// ---- s[u][d][b] = sum over 32 chunks, float4-vectorized ----
__global__ __launch_bounds__(256) void reduce_kernel(const float4* __restrict__ part4,
                                                     float4* __restrict__ s4) {
    int n = blockIdx.x * 256 + threadIdx.x;     // grid = 32 -> 8192 float4
    float4 a = part4[n];
#pragma unroll
    for (int k = 1; k < 32; ++k) {
        float4 b = part4[(size_t)k * 8192 + n];
        a.x += b.x; a.y += b.y; a.z += b.z; a.w += b.w;
    }
    s4[n] = a;
}

// ---- squash (reference quirk: mag over U per (b,d)); s layout [u][d][b] ----
__global__ __launch_bounds__(256) void v_kernel2(const float* __restrict__ s,
                                                 float* __restrict__ v,
                                                 float* __restrict__ out) {
    int n = blockIdx.x * 256 + threadIdx.x;     // grid = 4 -> 1024 = B*D
    int b = n >> 4, d = n & 15;
    float sv[32];
    float msq = 0.f;
#pragma unroll
    for (int u = 0; u < 32; ++u) {
        sv[u] = s[(u * 16 + d) * 64 + b];
        msq += sv[u] * sv[u];
    }
    float scale = msq / ((1.f + msq) * sqrtf(msq));
#pragma unroll
    for (int u = 0; u < 32; ++u) {
        float val = sv[u] * scale;
        v[(b * 32 + u) * 16 + d] = val;
        out[(b * 32 + u) * 16 + d] = val;
    }
}

// ---- delta + fused softmax ----
template <int FIRST>
__global__ __launch_bounds__(256) void delta_kernel6(const float* __restrict__ xt,
                                                     const float* __restrict__ W,
                                                     const float* __restrict__ v,
                                                     float* __restrict__ bij,
                                                     float* __restrict__ cij) {
    const int c0 = blockIdx.x * 2;
    const int t = threadIdx.x;
    __shared__ float xs[1024];                  // [cc][b][i]
    __shared__ float sm[64];
    {
        const float4 vq = reinterpret_cast<const float4*>(xt + (size_t)c0 * 512)[t];
        const float* pf = &vq.x;
        const int k = t * 4;
#pragma unroll
        for (int j2 = 0; j2 < 4; ++j2) {
            int e = k + j2, cl = e >> 9, rem = e & 511, i = rem >> 6, b = rem & 63;
            xs[cl * 512 + b * 8 + i] = pf[j2];
        }
    }
    __syncthreads();
    const int u = t >> 3, d0 = (t & 7) * 2;
    const float4* W0 = reinterpret_cast<const float4*>(W + ((size_t)c0 * 32 + u) * 128 + d0 * 8);
    const float4* W1 = reinterpret_cast<const float4*>(W + ((size_t)(c0 + 1) * 32 + u) * 128 + d0 * 8);
    const float4 a00 = W0[0], a01 = W0[1], a10 = W0[2], a11 = W0[3];
    const float4 b00 = W1[0], b01 = W1[1], b10 = W1[2], b11 = W1[3];
    float p0 = 0.f, p1 = 0.f;
#pragma unroll 4
    for (int b = 0; b < 64; ++b) {
        const float2 vv = *reinterpret_cast<const float2*>(v + (b * 32 + u) * 16 + d0);
        {
            const float4 xa = *reinterpret_cast<const float4*>(xs + b * 8);
            const float4 xb = *reinterpret_cast<const float4*>(xs + b * 8 + 4);
            float uh0 = a00.x * xa.x + a00.y * xa.y + a00.z * xa.z + a00.w * xa.w
                      + a01.x * xb.x + a01.y * xb.y + a01.z * xb.z + a01.w * xb.w;
            float uh1 = a10.x * xa.x + a10.y * xa.y + a10.z * xa.z + a10.w * xa.w
                      + a11.x * xb.x + a11.y * xb.y + a11.z * xb.z + a11.w * xb.w;
            p0 += uh0 * vv.x + uh1 * vv.y;
        }
        {
            const float4 xa = *reinterpret_cast<const float4*>(xs + 512 + b * 8);
            const float4 xb = *reinterpret_cast<const float4*>(xs + 512 + b * 8 + 4);
            float uh0 = b00.x * xa.x + b00.y * xa.y + b00.z * xa.z + b00.w * xa.w
                      + b01.x * xb.x + b01.y * xb.y + b01.z * xb.z + b01.w * xb.w;
            float uh1 = b10.x * xa.x + b10.y * xa.y + b10.z * xa.z + b10.w * xa.w
                      + b11.x * xb.x + b11.y * xb.y + b11.z * xb.z + b11.w * xb.w;
            p1 += uh0 * vv.x + uh1 * vv.y;
        }
    }
    p0 += __shfl_xor(p0, 1); p0 += __shfl_xor(p0, 2); p0 += __shfl_xor(p0, 4);
    p1 += __shfl_xor(p1, 1); p1 += __shfl_xor(p1, 2); p1 += __shfl_xor(p1, 4);
    if ((t & 7) == 0) {
        float r0 = p0 * (1.0f / 64.0f), r1 = p1 * (1.0f / 64.0f);
        if (!FIRST) { r0 += bij[c0 * 32 + u]; r1 += bij[(c0 + 1) * 32 + u]; }
        bij[c0 * 32 + u] = r0; bij[(c0 + 1) * 32 + u] = r1;
        sm[u] = r0; sm[32 + u] = r1;
    }
    __syncthreads();
    if (t < 64) {                                // wave 0: softmax per 32-lane half
        float val = sm[t];
        float m = val;
#pragma unroll
        for (int mask = 16; mask >= 1; mask >>= 1) m = fmaxf(m, __shfl_xor(m, mask));
        float e = expf(val - m);
        float ssum = e;
#pragma unroll
        for (int mask = 16; mask >= 1; mask >>= 1) ssum += __shfl_xor(ssum, mask);
        cij[(c0 + (t >> 5)) * 32 + (t & 31)] = e / ssum;
    }
}

extern "C" void kernel_launch(void* const* d_in, const int* in_sizes, int n_in,
                              void* d_out, int out_size, void* d_ws, size_t ws_size,
                              hipStream_t stream) {
    const float* x = (const float*)d_in[0];   // (B, I, C) = (64, 8, 2048)
    const float* W = (const float*)d_in[1];   // (C, U, D, I) = (2048, 32, 16, 8)
    float* out = (float*)d_out;               // (B, U, D, 1) flat = 32768 fp32

    float* ws   = (float*)d_ws;
    float* xt   = ws;                   // C*I*B    = 1,048,576 floats  [c][i][b]
    float* bij  = xt + 1048576;         // C*U      = 65,536
    float* cij  = bij + 65536;          // C*U      = 65,536
    float* s    = cij + 65536;          // U*D*B    = 32,768
    float* v    = s + 32768;            // B*U*D    = 32,768
    float* part = v + 32768;            // 32*U*D*B = 1,048,576

    transpose_kernel<<<256, 256, 0, stream>>>(x, xt);

    // it 0: cij uniform 1/32 (bij=0); delta writes bij and produces cij
    s_kernel7<1><<<1024, 256, 0, stream>>>(xt, W, cij, part);
    reduce_kernel<<<32, 256, 0, stream>>>((const float4*)part, (float4*)s);
    v_kernel2<<<4, 256, 0, stream>>>(s, v, out);
    delta_kernel6<1><<<1024, 256, 0, stream>>>(xt, W, v, bij, cij);

    // it 1
    s_kernel7<0><<<1024, 256, 0, stream>>>(xt, W, cij, part);
    reduce_kernel<<<32, 256, 0, stream>>>((const float4*)part, (float4*)s);
    v_kernel2<<<4, 256, 0, stream>>>(s, v, out);
    delta_kernel6<0><<<1024, 256, 0, stream>>>(xt, W, v, bij, cij);

    // it 2
    s_kernel7<0><<<1024, 256, 0, stream>>>(xt, W, cij, part);
    reduce_kernel<<<32, 256, 0, stream>>>((const float4*)part, (float4*)s);
    v_kernel2<<<4, 256, 0, stream>>>(s, v, out);
}